// Round 9
// baseline (79.519 us; speedup 1.0000x reference)
//
#include <hip/hip_runtime.h>

// Problem constants
constexpr int NB  = 1024;
constexpr int NIN = 512;
constexpr int NJ  = 64;
constexpr int NK  = 8;
constexpr int NC  = NJ * NK;          // 512
constexpr int OUTC = NIN + NJ;        // 576
constexpr float EXPN10 = 4.5399929762484854e-05f;
constexpr float FEAT_BASE = 1024.0f * EXPN10;

typedef __bf16 bf16x8 __attribute__((ext_vector_type(8)));
typedef float floatx16 __attribute__((ext_vector_type(16)));

__device__ __forceinline__ unsigned f2bf(float f) {  // RNE fp32->bf16
  unsigned u = __float_as_uint(f);
  u += 0x7FFFu + ((u >> 16) & 1u);
  return u >> 16;
}

// ---------------------------------------------------------------------------
// Kernel 1 (gemm_fused): byte-identical to R8 (best measured: full-machine
// 256 blocks, tile 64b x 32c, K-split 2-way across wave pairs, 2 staged
// phases). R8 proved phase count / CU coverage is the gemm lever (-2.3us).
// ---------------------------------------------------------------------------
__global__ __launch_bounds__(256) void gemm_fused(const float* __restrict__ x,
                                                  const float* __restrict__ T,
                                                  float* __restrict__ Mp,
                                                  uint4* __restrict__ Mb,
                                                  float* __restrict__ na,
                                                  float* __restrict__ out) {
  __shared__ __align__(16) ushort smem_u[2 * 64 * 136 + 2 * 32 * 136];  // 52224 B
  ushort* Xs = smem_u;                     // [2][64][136] bf16 A halves
  ushort* Ts = smem_u + 2 * 64 * 136;      // [2][32][136] bf16 B halves (transposed)
  float*  Cs = (float*)smem_u;             // [2][64][36] fp32 partial tiles (overlay)

  const int tid = threadIdx.x;
  const int b0 = blockIdx.x * 64;
  const int c0 = blockIdx.y * 32;

  const int lane = tid & 63;
  const int w    = tid >> 6;
  const int l31  = lane & 31;
  const int half = lane >> 5;
  const int wr   = w & 1;        // arow half
  const int kh   = w >> 1;       // K half owned by this wave
  const int arow = wr * 32 + l31;

  // B-transpose thread mapping
  const int bk = tid >> 3;        // 0..31 : k-pair index within 64-row group
  const int bc = (tid & 7) * 4;   // 0..28 : c-quad offset

  // ---- out init (256 blocks x 576 float4) ----
  const int bidf = blockIdx.y * 16 + blockIdx.x;   // 0..255
#pragma unroll
  for (int it = 0; it < 3; ++it) {
    const int li = it * 256 + tid;
    if (li < 576) {
      const int gi = bidf * 576 + li;
      const int b = gi / (OUTC / 4);                 // /144 -> magic mul
      const int r = gi - b * (OUTC / 4);
      float4 v;
      if (r < NIN / 4) v = ((const float4*)x)[b * (NIN / 4) + r];
      else v = float4{FEAT_BASE, FEAT_BASE, FEAT_BASE, FEAT_BASE};
      ((float4*)out)[gi] = v;
    }
  }

  floatx16 acc = {};

  for (int z = 0; z < 2; ++z) {
    // ======== load phase: ALL global loads for BOTH K-halves batched ========
    float4 av[16];
#pragma unroll
    for (int kk = 0; kk < 2; ++kk) {
#pragma unroll
      for (int t = 0; t < 4; ++t) {
        const int u = t * 256 + tid;
        const int row = u >> 4, seg = u & 15;
        const size_t base = (size_t)(b0 + row) * NIN + (kk * 2 + z) * 128 + seg * 8;
        av[kk * 8 + 2 * t]     = *(const float4*)&x[base];
        av[kk * 8 + 2 * t + 1] = *(const float4*)&x[base + 4];
      }
    }
    float4 bv[8];
#pragma unroll
    for (int kk = 0; kk < 2; ++kk) {
#pragma unroll
      for (int it = 0; it < 2; ++it) {
        const int k0 = it * 64 + bk * 2;             // local k (even), 0..126
        const size_t base = (size_t)((kk * 2 + z) * 128 + k0) * NC + c0 + bc;
        bv[kk * 4 + 2 * it]     = *(const float4*)&T[base];      // row k0
        bv[kk * 4 + 2 * it + 1] = *(const float4*)&T[base + NC]; // row k0+1
      }
    }

    // ======== write phase: convert + LDS ========
#pragma unroll
    for (int kk = 0; kk < 2; ++kk) {
#pragma unroll
      for (int t = 0; t < 4; ++t) {
        const int u = t * 256 + tid;
        const int row = u >> 4, seg = u & 15;
        uint4 p;
        p.x = f2bf(av[kk * 8 + 2 * t].x) | (f2bf(av[kk * 8 + 2 * t].y) << 16);
        p.y = f2bf(av[kk * 8 + 2 * t].z) | (f2bf(av[kk * 8 + 2 * t].w) << 16);
        p.z = f2bf(av[kk * 8 + 2 * t + 1].x) | (f2bf(av[kk * 8 + 2 * t + 1].y) << 16);
        p.w = f2bf(av[kk * 8 + 2 * t + 1].z) | (f2bf(av[kk * 8 + 2 * t + 1].w) << 16);
        *(uint4*)&Xs[kk * 64 * 136 + row * 136 + seg * 8] = p;
      }
      unsigned* Tw = (unsigned*)(Ts + kk * 32 * 136);   // dword view, row stride 68
#pragma unroll
      for (int it = 0; it < 2; ++it) {
        const float* lo = &bv[kk * 4 + 2 * it].x;
        const float* hi = &bv[kk * 4 + 2 * it + 1].x;
#pragma unroll
        for (int q = 0; q < 4; ++q) {
          const unsigned val = f2bf(lo[q]) | (f2bf(hi[q]) << 16);
          Tw[(bc + q) * 68 + it * 32 + bk] = val;      // Ts[kk][c][k0..k0+1]
        }
      }
    }

    __syncthreads();

    // ---- MFMA: 8 steps of K=16 on this wave's K-half ----
#pragma unroll
    for (int s = 0; s < 8; ++s) {
      const bf16x8 af = *(const bf16x8*)&Xs[kh * 64 * 136 + arow * 136 + s * 16 + half * 8];
      const bf16x8 bf = *(const bf16x8*)&Ts[kh * 32 * 136 + l31 * 136 + s * 16 + half * 8];
      acc = __builtin_amdgcn_mfma_f32_32x32x16_bf16(af, bf, acc, 0, 0, 0);
    }
    __syncthreads();
  }

  // ---- epilogue: partials -> Cs[kh], sync, sum + emit ----
#pragma unroll
  for (int reg = 0; reg < 16; ++reg) {
    const int row = (reg & 3) + 8 * (reg >> 2) + 4 * half;
    Cs[kh * 64 * 36 + (wr * 32 + row) * 36 + l31] = acc[reg];
  }
  __syncthreads();

  {
    const int jl = tid >> 6;                // local j 0..3
    const int b  = tid & 63;                // local b
    const float4 p0 = *(const float4*)&Cs[b * 36 + jl * 8];
    const float4 p1 = *(const float4*)&Cs[b * 36 + jl * 8 + 4];
    const float4 q0 = *(const float4*)&Cs[64 * 36 + b * 36 + jl * 8];
    const float4 q1 = *(const float4*)&Cs[64 * 36 + b * 36 + jl * 8 + 4];
    const float4 m0 = float4{p0.x + q0.x, p0.y + q0.y, p0.z + q0.z, p0.w + q0.w};
    const float4 m1 = float4{p1.x + q1.x, p1.y + q1.y, p1.z + q1.z, p1.w + q1.w};
    const int j_g = blockIdx.y * 4 + jl;
    const int idx = j_g * NB + b0 + b;
    ((float4*)Mp)[idx * 2]     = m0;
    ((float4*)Mp)[idx * 2 + 1] = m1;
    float s = m0.x * m0.x;
    s = fmaf(m0.y, m0.y, s); s = fmaf(m0.z, m0.z, s); s = fmaf(m0.w, m0.w, s);
    s = fmaf(m1.x, m1.x, s); s = fmaf(m1.y, m1.y, s); s = fmaf(m1.z, m1.z, s);
    s = fmaf(m1.w, m1.w, s);
    na[idx] = s;
    uint4 pk;
    pk.x = f2bf(m0.x) | (f2bf(m0.y) << 16);
    pk.y = f2bf(m0.z) | (f2bf(m0.w) << 16);
    pk.z = f2bf(m1.x) | (f2bf(m1.y) << 16);
    pk.w = f2bf(m1.z) | (f2bf(m1.w) << 16);
    Mb[idx] = pk;
  }
}

// ---------------------------------------------------------------------------
// Kernel 2: pairwise R9 — COARSENED: grid (64 j, 2 bh, 2 ag-half) = 256 fat
// blocks (was 1024 thin). Evidence: R7 (more/thinner blocks) -1.9us, R6
// (longer per-wave chains, same count) -7.5us => per-block fixed overhead
// dominates. Each block stages Mb/nb ONCE (one barrier), then loops 4 ag
// values with ZERO further barriers: a-fragment (32 uint4) and 16 norm
// scalars re-read per-ag straight from L2 (tiny). Inner 16-bt MFMA +
// prefilter body byte-identical to the proven kernel; same flagged pair set,
// same atomics, same numerics.
// ---------------------------------------------------------------------------
__global__ __launch_bounds__(256) void pairwise_kernel(const uint4* __restrict__ Mb,
                                                       const float* __restrict__ na,
                                                       const float* __restrict__ Mp,
                                                       float* __restrict__ out) {
  const int j    = blockIdx.x;
  const int bh   = blockIdx.y;
  const int agh  = blockIdx.z;
  const int tid  = threadIdx.x;
  const int lane = tid & 63;
  const int w    = tid >> 6;
  const int col  = lane & 31;
  const int h    = lane >> 5;
  const int jb   = j * NB;

  __shared__ uint4 Mb_s[513];    // [512] = zeros for K-pad lanes
  __shared__ float nb_s[512];

  const int bbeg = bh * 512;
  Mb_s[tid]       = Mb[jb + bbeg + tid];
  Mb_s[tid + 256] = Mb[jb + bbeg + tid + 256];
  nb_s[tid]       = na[jb + bbeg + tid];
  nb_s[tid + 256] = na[jb + bbeg + tid + 256];
  if (tid == 0) Mb_s[512] = uint4{0u, 0u, 0u, 0u};

  __syncthreads();

  const floatx16 zero = {};

#pragma unroll
  for (int agi = 0; agi < 4; ++agi) {
    const int ag = agh * 4 + agi;
    const int a0 = ag * 128 + w * 32;

    uint4 araw = uint4{0u, 0u, 0u, 0u};
    if (lane < 32) araw = Mb[jb + a0 + lane];
    const bf16x8 af = __builtin_bit_cast(bf16x8, araw);

    float c995[16];
#pragma unroll
    for (int reg = 0; reg < 16; ++reg) {
      const int row = (reg & 3) + 8 * (reg >> 2) + 4 * h;
      c995[reg] = 0.995f * na[jb + a0 + row];
    }

#pragma unroll 2
    for (int bt = 0; bt < 16; ++bt) {
      const int bidx = bt * 32 + col;
      const uint4 braw = Mb_s[lane < 32 ? bidx : 512];
      const bf16x8 bf = __builtin_bit_cast(bf16x8, braw);
      const floatx16 P = __builtin_amdgcn_mfma_f32_32x32x16_bf16(af, bf, zero, 0, 0, 0);
      const float nb_l = nb_s[bidx];
      const float rhs = 100.0f - 0.995f * nb_l;

      float t = fmaf(-2.0f, P[0], c995[0]);
#pragma unroll
      for (int reg = 1; reg < 16; ++reg)
        t = fminf(t, fmaf(-2.0f, P[reg], c995[reg]));

      if (__any(t < rhs)) {   // rare: ~diagonal tiles only
#pragma unroll
        for (int reg = 0; reg < 16; ++reg) {
          if (fmaf(-2.0f, P[reg], c995[reg]) < rhs) {
            const int row = (reg & 3) + 8 * (reg >> 2) + 4 * h;
            const int a = a0 + row;
            const int b = bbeg + bt * 32 + col;
            float corr;
            if (a == b) {
              corr = 1.0f - EXPN10;
            } else {
              const float4 av0 = ((const float4*)Mp)[(jb + a) * 2];
              const float4 av1 = ((const float4*)Mp)[(jb + a) * 2 + 1];
              const float4 bv0 = ((const float4*)Mp)[(jb + b) * 2];
              const float4 bv1 = ((const float4*)Mp)[(jb + b) * 2 + 1];
              float d = av0.x - bv0.x; float sq = d * d;
              d = av0.y - bv0.y; sq = fmaf(d, d, sq);
              d = av0.z - bv0.z; sq = fmaf(d, d, sq);
              d = av0.w - bv0.w; sq = fmaf(d, d, sq);
              d = av1.x - bv1.x; sq = fmaf(d, d, sq);
              d = av1.y - bv1.y; sq = fmaf(d, d, sq);
              d = av1.z - bv1.z; sq = fmaf(d, d, sq);
              d = av1.w - bv1.w; sq = fmaf(d, d, sq);
              const float nrm = sqrtf(sq);
              corr = (nrm < 10.0f) ? (__expf(-nrm) - EXPN10) : 0.0f;
            }
            if (corr != 0.0f) atomicAdd(&out[a * OUTC + NIN + j], corr);
          }
        }
      }
    }
  }
}

// ---------------------------------------------------------------------------
extern "C" void kernel_launch(void* const* d_in, const int* in_sizes, int n_in,
                              void* d_out, int out_size, void* d_ws, size_t ws_size,
                              hipStream_t stream) {
  const float* x = (const float*)d_in[0];
  const float* T = (const float*)d_in[1];
  float* out = (float*)d_out;

  // workspace layout (3.25 MB)
  float* Mp  = (float*)d_ws;                         // [64][1024][8] fp32   2 MB
  float* na  = Mp + (size_t)NJ * NB * NK;            // [64][1024]         256 KB
  uint4* Mb  = (uint4*)(na + (size_t)NJ * NB);       // [64][1024] bf16x8    1 MB

  gemm_fused<<<dim3(16, 16), 256, 0, stream>>>(x, T, Mp, Mb, na, out);
  pairwise_kernel<<<dim3(NJ, 2, 2), 256, 0, stream>>>(Mb, na, Mp, out);
}

// Round 10
// 72.585 us; speedup vs baseline: 1.0955x; 1.0955x over previous
//
#include <hip/hip_runtime.h>

// Problem constants
constexpr int NB  = 1024;
constexpr int NIN = 512;
constexpr int NJ  = 64;
constexpr int NK  = 8;
constexpr int NC  = NJ * NK;          // 512
constexpr int OUTC = NIN + NJ;        // 576
constexpr float EXPN10 = 4.5399929762484854e-05f;
constexpr float FEAT_BASE = 1024.0f * EXPN10;

typedef __bf16 bf16x8 __attribute__((ext_vector_type(8)));
typedef float floatx16 __attribute__((ext_vector_type(16)));

__device__ __forceinline__ unsigned f2bf(float f) {  // RNE fp32->bf16
  unsigned u = __float_as_uint(f);
  u += 0x7FFFu + ((u >> 16) & 1u);
  return u >> 16;
}

// ---------------------------------------------------------------------------
// Kernel 1 (gemm_fused) R10: tile 32b x 32c, grid 32x16 = 512 blocks =
// 2 blocks/CU = 2 waves/SIMD (TLP!), K-split 4-way across the block's 4
// waves, ONE staged phase (all K=512 at once, 68KB LDS as 4 proven
// [32][136] slices), then 8 MFMAs, then 4-partial reduction.
// Session law this encodes: every regression (R3/R6/R9) was a 1-wave/SIMD
// serial-latency config; the one win (R8) cut staged phase count. This
// combines max phase-cut (2->1) with restored TLP (2 waves/SIMD).
// ---------------------------------------------------------------------------
__global__ __launch_bounds__(256, 2) void gemm_fused(const float* __restrict__ x,
                                                     const float* __restrict__ T,
                                                     float* __restrict__ Mp,
                                                     uint4* __restrict__ Mb,
                                                     float* __restrict__ na,
                                                     float* __restrict__ out) {
  __shared__ __align__(16) ushort smem_u[2 * 4 * 32 * 136];   // 69632 B
  ushort* Xs = smem_u;                  // [4][32][136] bf16 A K-slices
  ushort* Ts = smem_u + 4 * 32 * 136;   // [4][32][136] bf16 B K-slices (transposed)
  float*  Cs = (float*)smem_u;          // [4][32][36] fp32 partials (overlay)

  const int tid = threadIdx.x;
  const int b0 = blockIdx.x * 32;
  const int c0 = blockIdx.y * 32;

  const int lane = tid & 63;
  const int w    = tid >> 6;        // wave = K-quarter owner
  const int l31  = lane & 31;
  const int half = lane >> 5;

  // ---- out init (512 blocks x 288 float4) ----
  const int bidf = blockIdx.y * 32 + blockIdx.x;   // 0..511
  {
    const int gi0 = bidf * 288;
#pragma unroll
    for (int it = 0; it < 2; ++it) {
      const int li = it * 256 + tid;
      if (li < 288) {
        const int gi = gi0 + li;
        const int b = gi / (OUTC / 4);               // /144 -> magic mul
        const int r = gi - b * (OUTC / 4);
        float4 v;
        if (r < NIN / 4) v = ((const float4*)x)[b * (NIN / 4) + r];
        else v = float4{FEAT_BASE, FEAT_BASE, FEAT_BASE, FEAT_BASE};
        ((float4*)out)[gi] = v;
      }
    }
  }

  // ======== load phase: ALL K=512 for both A and B, batched ========
  float4 av[16];
#pragma unroll
  for (int t = 0; t < 8; ++t) {
    const int u = t * 256 + tid;             // 0..2047
    const int kq  = u >> 9;                  // = t>>1
    const int row = (u >> 4) & 31;
    const int seg = u & 15;
    const size_t base = (size_t)(b0 + row) * NIN + kq * 128 + seg * 8;
    av[2 * t]     = *(const float4*)&x[base];
    av[2 * t + 1] = *(const float4*)&x[base + 4];
  }
  float4 bv[16];
#pragma unroll
  for (int it = 0; it < 8; ++it) {
    const int k0 = it * 64 + (tid >> 3) * 2;          // even k, 0..510
    const size_t base = (size_t)k0 * NC + c0 + (tid & 7) * 4;
    bv[2 * it]     = *(const float4*)&T[base];         // row k0
    bv[2 * it + 1] = *(const float4*)&T[base + NC];    // row k0+1
  }

  // ======== write phase: convert + LDS ========
#pragma unroll
  for (int t = 0; t < 8; ++t) {
    const int u = t * 256 + tid;
    const int kq  = u >> 9;
    const int row = (u >> 4) & 31;
    const int seg = u & 15;
    uint4 p;
    p.x = f2bf(av[2 * t].x) | (f2bf(av[2 * t].y) << 16);
    p.y = f2bf(av[2 * t].z) | (f2bf(av[2 * t].w) << 16);
    p.z = f2bf(av[2 * t + 1].x) | (f2bf(av[2 * t + 1].y) << 16);
    p.w = f2bf(av[2 * t + 1].z) | (f2bf(av[2 * t + 1].w) << 16);
    *(uint4*)&Xs[kq * 32 * 136 + row * 136 + seg * 8] = p;
  }
#pragma unroll
  for (int it = 0; it < 8; ++it) {
    const int kq = it >> 1;                           // k0>>7, uniform per it
    const int kd = (it & 1) * 32 + (tid >> 3);        // dword index k'/2
    unsigned* Tw = (unsigned*)(Ts + kq * 32 * 136);   // dword view, row stride 68
    const float* lo = &bv[2 * it].x;
    const float* hi = &bv[2 * it + 1].x;
#pragma unroll
    for (int q = 0; q < 4; ++q) {
      const unsigned val = f2bf(lo[q]) | (f2bf(hi[q]) << 16);
      Tw[((tid & 7) * 4 + q) * 68 + kd] = val;        // Ts[kq][c][k']
    }
  }

  __syncthreads();

  // ---- MFMA: 8 steps of K=16 on this wave's K-quarter ----
  floatx16 acc = {};
#pragma unroll
  for (int s = 0; s < 8; ++s) {
    const bf16x8 af = *(const bf16x8*)&Xs[w * 32 * 136 + l31 * 136 + s * 16 + half * 8];
    const bf16x8 bf = *(const bf16x8*)&Ts[w * 32 * 136 + l31 * 136 + s * 16 + half * 8];
    acc = __builtin_amdgcn_mfma_f32_32x32x16_bf16(af, bf, acc, 0, 0, 0);
  }
  __syncthreads();

  // ---- epilogue: partials -> Cs[w][b][c], sync, 4-sum + emit ----
#pragma unroll
  for (int reg = 0; reg < 16; ++reg) {
    const int row = (reg & 3) + 8 * (reg >> 2) + 4 * half;
    Cs[w * 32 * 36 + row * 36 + l31] = acc[reg];      // [b=row][c=l31]
  }
  __syncthreads();

  if (tid < 128) {
    const int b  = tid & 31;                // local b
    const int jl = tid >> 5;                // local j 0..3 (c cols jl*8..+7)
    float4 m0 = float4{0.f, 0.f, 0.f, 0.f};
    float4 m1 = float4{0.f, 0.f, 0.f, 0.f};
#pragma unroll
    for (int kq = 0; kq < 4; ++kq) {
      const float4 p0 = *(const float4*)&Cs[kq * 32 * 36 + b * 36 + jl * 8];
      const float4 p1 = *(const float4*)&Cs[kq * 32 * 36 + b * 36 + jl * 8 + 4];
      m0.x += p0.x; m0.y += p0.y; m0.z += p0.z; m0.w += p0.w;
      m1.x += p1.x; m1.y += p1.y; m1.z += p1.z; m1.w += p1.w;
    }
    const int j_g = blockIdx.y * 4 + jl;
    const int idx = j_g * NB + b0 + b;
    ((float4*)Mp)[idx * 2]     = m0;
    ((float4*)Mp)[idx * 2 + 1] = m1;
    float s = m0.x * m0.x;
    s = fmaf(m0.y, m0.y, s); s = fmaf(m0.z, m0.z, s); s = fmaf(m0.w, m0.w, s);
    s = fmaf(m1.x, m1.x, s); s = fmaf(m1.y, m1.y, s); s = fmaf(m1.z, m1.z, s);
    s = fmaf(m1.w, m1.w, s);
    na[idx] = s;
    uint4 pk;
    pk.x = f2bf(m0.x) | (f2bf(m0.y) << 16);
    pk.y = f2bf(m0.z) | (f2bf(m0.w) << 16);
    pk.z = f2bf(m1.x) | (f2bf(m1.y) << 16);
    pk.w = f2bf(m1.z) | (f2bf(m1.w) << 16);
    Mb[idx] = pk;
  }
}

// ---------------------------------------------------------------------------
// Kernel 2: pairwise — byte-identical to the PROVEN best (73.7us baseline
// version; 1024 blocks = 4 waves/SIMD TLP sweet spot. R6 -7.5, R7 -1.9,
// R9 -7.4 all deviations regressed).
// ---------------------------------------------------------------------------
__global__ __launch_bounds__(256) void pairwise_kernel(const uint4* __restrict__ Mb,
                                                       const float* __restrict__ na,
                                                       const float* __restrict__ Mp,
                                                       float* __restrict__ out) {
  const int j    = blockIdx.x;
  const int ag   = blockIdx.y;
  const int bh   = blockIdx.z;
  const int tid  = threadIdx.x;
  const int lane = tid & 63;
  const int w    = tid >> 6;
  const int col  = lane & 31;
  const int h    = lane >> 5;
  const int jb   = j * NB;

  __shared__ uint4 Mb_s[513];    // [512] = zeros for K-pad lanes
  __shared__ float nb_s[512];
  __shared__ float na_s[128];

  const int bbeg = bh * 512;
  Mb_s[tid]       = Mb[jb + bbeg + tid];
  Mb_s[tid + 256] = Mb[jb + bbeg + tid + 256];
  nb_s[tid]       = na[jb + bbeg + tid];
  nb_s[tid + 256] = na[jb + bbeg + tid + 256];
  if (tid == 0) Mb_s[512] = uint4{0u, 0u, 0u, 0u};

  const int a0 = ag * 128 + w * 32;
  if (lane < 32) na_s[w * 32 + lane] = na[jb + a0 + lane];

  uint4 araw = uint4{0u, 0u, 0u, 0u};
  if (lane < 32) araw = Mb[jb + a0 + lane];
  const bf16x8 af = __builtin_bit_cast(bf16x8, araw);

  __syncthreads();

  float c995[16];
#pragma unroll
  for (int reg = 0; reg < 16; ++reg) {
    const int row = (reg & 3) + 8 * (reg >> 2) + 4 * h;
    c995[reg] = 0.995f * na_s[w * 32 + row];
  }

  const floatx16 zero = {};

#pragma unroll 2
  for (int bt = 0; bt < 16; ++bt) {
    const int bidx = bt * 32 + col;
    const uint4 braw = Mb_s[lane < 32 ? bidx : 512];
    const bf16x8 bf = __builtin_bit_cast(bf16x8, braw);
    const floatx16 P = __builtin_amdgcn_mfma_f32_32x32x16_bf16(af, bf, zero, 0, 0, 0);
    const float nb_l = nb_s[bidx];
    const float rhs = 100.0f - 0.995f * nb_l;

    float t = fmaf(-2.0f, P[0], c995[0]);
#pragma unroll
    for (int reg = 1; reg < 16; ++reg)
      t = fminf(t, fmaf(-2.0f, P[reg], c995[reg]));

    if (__any(t < rhs)) {   // rare: ~diagonal tiles only
#pragma unroll
      for (int reg = 0; reg < 16; ++reg) {
        if (fmaf(-2.0f, P[reg], c995[reg]) < rhs) {
          const int row = (reg & 3) + 8 * (reg >> 2) + 4 * h;
          const int a = a0 + row;
          const int b = bbeg + bt * 32 + col;
          float corr;
          if (a == b) {
            corr = 1.0f - EXPN10;
          } else {
            const float4 av0 = ((const float4*)Mp)[(jb + a) * 2];
            const float4 av1 = ((const float4*)Mp)[(jb + a) * 2 + 1];
            const float4 bv0 = ((const float4*)Mp)[(jb + b) * 2];
            const float4 bv1 = ((const float4*)Mp)[(jb + b) * 2 + 1];
            float d = av0.x - bv0.x; float sq = d * d;
            d = av0.y - bv0.y; sq = fmaf(d, d, sq);
            d = av0.z - bv0.z; sq = fmaf(d, d, sq);
            d = av0.w - bv0.w; sq = fmaf(d, d, sq);
            d = av1.x - bv1.x; sq = fmaf(d, d, sq);
            d = av1.y - bv1.y; sq = fmaf(d, d, sq);
            d = av1.z - bv1.z; sq = fmaf(d, d, sq);
            d = av1.w - bv1.w; sq = fmaf(d, d, sq);
            const float nrm = sqrtf(sq);
            corr = (nrm < 10.0f) ? (__expf(-nrm) - EXPN10) : 0.0f;
          }
          if (corr != 0.0f) atomicAdd(&out[a * OUTC + NIN + j], corr);
        }
      }
    }
  }
}

// ---------------------------------------------------------------------------
extern "C" void kernel_launch(void* const* d_in, const int* in_sizes, int n_in,
                              void* d_out, int out_size, void* d_ws, size_t ws_size,
                              hipStream_t stream) {
  const float* x = (const float*)d_in[0];
  const float* T = (const float*)d_in[1];
  float* out = (float*)d_out;

  // workspace layout (3.25 MB)
  float* Mp  = (float*)d_ws;                         // [64][1024][8] fp32   2 MB
  float* na  = Mp + (size_t)NJ * NB * NK;            // [64][1024]         256 KB
  uint4* Mb  = (uint4*)(na + (size_t)NJ * NB);       // [64][1024] bf16x8    1 MB

  gemm_fused<<<dim3(32, 16), 256, 0, stream>>>(x, T, Mp, Mb, na, out);
  pairwise_kernel<<<dim3(NJ, 8, 2), 256, 0, stream>>>(Mb, na, Mp, out);
}